// Round 8
// baseline (315.564 us; speedup 1.0000x reference)
//
#include <hip/hip_runtime.h>
#include <hip/hip_bf16.h>
#include <math.h>

#define NN 20000
#define NE 320000

typedef __attribute__((ext_vector_type(8))) short bf16x8;
typedef __attribute__((ext_vector_type(4))) float f32x4;

__device__ inline float bf2f_lo(uint v) {
    union { uint i; float f; } c; c.i = v << 16; return c.f;
}
__device__ inline float bf2f_hi(uint v) {
    union { uint i; float f; } c; c.i = v & 0xffff0000u; return c.f;
}
__device__ inline ushort f2bf(float f) {
    __hip_bfloat16 h = __float2bfloat16(f);
    return *reinterpret_cast<ushort*>(&h);
}

// ---------------- fused count + scan (last-block-done) ----------------
__global__ __launch_bounds__(256) void count_scan(const int* __restrict__ dst,
                                                  int* __restrict__ counts,
                                                  int* __restrict__ offsets,
                                                  int* __restrict__ cursor,
                                                  int* __restrict__ done) {
    int e = blockIdx.x * 256 + threadIdx.x;
    if (e < NE) atomicAdd(&counts[dst[e]], 1);
    __syncthreads();
    __shared__ bool amLast;
    if (threadIdx.x == 0) {
        __threadfence();
        amLast = (atomicAdd(done, 1) == (int)gridDim.x - 1);
    }
    __syncthreads();
    if (!amLast) return;
    __threadfence();
    // scan 20000 counts with 256 threads, 79 elems each
    __shared__ int part[256];
    int t = threadIdx.x;
    int begin = t * 79;
    int end = begin + 79 < NN ? begin + 79 : NN;
    if (begin > NN) begin = NN;
    int s = 0;
    for (int i = begin; i < end; ++i)
        s += __hip_atomic_load(&counts[i], __ATOMIC_RELAXED, __HIP_MEMORY_SCOPE_AGENT);
    part[t] = s;
    __syncthreads();
    for (int off = 1; off < 256; off <<= 1) {
        int v = (t >= off) ? part[t - off] : 0;
        __syncthreads();
        part[t] += v;
        __syncthreads();
    }
    int run = (t == 0) ? 0 : part[t - 1];
    for (int i = begin; i < end; ++i) {
        int c = __hip_atomic_load(&counts[i], __ATOMIC_RELAXED, __HIP_MEMORY_SCOPE_AGENT);
        offsets[i] = run;
        cursor[i] = run;
        run += c;
    }
    if (t == 255) offsets[NN] = part[255];
}

// pass 1: scatter ONLY the 4-byte edge index into CSR position order
__global__ void fill1_kernel(const int* __restrict__ dst, int* __restrict__ cursor,
                             int* __restrict__ csr_eidx) {
    int e = blockIdx.x * blockDim.x + threadIdx.x;
    if (e >= NE) return;
    int pos = atomicAdd(&cursor[dst[e]], 1);
    csr_eidx[pos] = e;
}

struct EdgeParams {
    const float *pw0, *pb0, *mu0, *is0;
    const float *pw1, *pb1, *mu1, *is1;
    const float *pw2, *pb2, *mu2, *is2;
};

__device__ inline float fast_tanh(float x) {
    x = fminf(fmaxf(x, -9.f), 9.f);
    float e = __expf(2.f * x);
    return 1.f - 2.f / (e + 1.f);
}

__device__ inline void layer_w(float p0, float p1, const float* pw, const float* pb,
                               const float* mu, const float* is, float* out4) {
    float u0 = fast_tanh(p0 * pw[0] + p1 * pw[2] + pb[0]);
    float u1 = fast_tanh(p0 * pw[1] + p1 * pw[3] + pb[1]);
#pragma unroll
    for (int k = 0; k < 4; ++k) {
        float d0 = (u0 - mu[k * 2 + 0]) * is[k * 2 + 0];
        float d1 = (u1 - mu[k * 2 + 1]) * is[k * 2 + 1];
        out4[k] = __expf(-0.5f * (d0 * d0 + d1 * d1));
    }
}

// -------- fused: fill2 (blocks 0..1249) + weight transpose (blocks 1250..1889) --------
__global__ void fill2_prep(const int* __restrict__ csr_eidx, const int* __restrict__ src,
                           const float* __restrict__ pseudo, EdgeParams P,
                           int* __restrict__ csr_src, float* __restrict__ csr_w,
                           const float* __restrict__ f0, const float* __restrict__ f1,
                           const float* __restrict__ f2, ushort* __restrict__ w0,
                           ushort* __restrict__ w1, ushort* __restrict__ w2) {
    int bid = blockIdx.x;
    if (bid < 1250) {
        int i = bid * 256 + threadIdx.x;  // 1250*256 == NE exactly
        int e = csr_eidx[i];
        float2 p = *(const float2*)(pseudo + (size_t)e * 2);
        csr_src[i] = src[e];
        float w[4];
        layer_w(p.x, p.y, P.pw0, P.pb0, P.mu0, P.is0, w);
        *(float4*)(csr_w + (size_t)(0 * NE + i) * 4) = make_float4(w[0], w[1], w[2], w[3]);
        layer_w(p.x, p.y, P.pw1, P.pb1, P.mu1, P.is1, w);
        *(float4*)(csr_w + (size_t)(1 * NE + i) * 4) = make_float4(w[0], w[1], w[2], w[3]);
        layer_w(p.x, p.y, P.pw2, P.pb2, P.mu2, P.is2, w);
        *(float4*)(csr_w + (size_t)(2 * NE + i) * 4) = make_float4(w[0], w[1], w[2], w[3]);
    } else {
        int idx = (bid - 1250) * 256 + threadIdx.x;  // 640 blocks cover 163840 exactly
        const float* srcp;
        ushort* dstp;
        int din, KD, li;
        if (idx < 128 * 256) {
            srcp = f0; dstp = w0; din = 64; KD = 256; li = idx;
        } else if (idx < 128 * 256 + 128 * 512) {
            srcp = f1; dstp = w1; din = 128; KD = 512; li = idx - 128 * 256;
        } else {
            srcp = f2; dstp = w2; din = 128; KD = 512; li = idx - 128 * 256 - 128 * 512;
        }
        int n = li / KD;
        int r = li - n * KD;
        int k = r / din;
        int d = r - k * din;
        dstp[li] = f2bf(srcp[d * 512 + k * 128 + n]);
    }
}

// ---------------- fused layer: LDS-staged edge metadata + agg + MFMA GEMM ----------------
// block = 256 threads (4 waves), 16 nodes; wave w aggs nodes 4w..4w+3, then GEMM cols 32w..32w+31.
template <int DIN, bool INF32, bool OUTBF>
__global__ __launch_bounds__(256) void layer_fused(const void* __restrict__ hin,
                                                   const int* __restrict__ offsets,
                                                   const int* __restrict__ csr_src,
                                                   const float* __restrict__ csr_w,
                                                   const ushort* __restrict__ Bt,
                                                   const float* __restrict__ bias,
                                                   void* __restrict__ hout) {
    constexpr int KD = 4 * DIN;
    constexpr int PITCH = KD + 8;  // ushorts; 16B-aligned rows
    constexpr int CAP = 768;       // staged-edge capacity (mean/block = 256)
    __shared__ __align__(16) ushort Ts[16 * PITCH];
    __shared__ int Sld[CAP];
    __shared__ __align__(16) float Wld[CAP * 4];
    int wv = threadIdx.x >> 6, lane = threadIdx.x & 63;
    int l16 = lane & 15, quad = lane >> 4;
    int nb = blockIdx.x * 16;
    int base = offsets[nb];
    int Eblk = offsets[nb + 16] - base;

    // cooperative stage of this block's edge metadata (contiguous CSR range)
    int Estage = Eblk < CAP ? Eblk : CAP;
    for (int i = threadIdx.x; i < Estage; i += 256) {
        Sld[i] = csr_src[base + i];
        *(float4*)(Wld + i * 4) = *(const float4*)(csr_w + (size_t)(base + i) * 4);
    }
    __syncthreads();

    // ---- aggregation phase ----
#pragma unroll
    for (int j = 0; j < 4; ++j) {
        int row = wv * 4 + j;
        int n = nb + row;
        int b = offsets[n] - base, eN = offsets[n + 1] - base;
        bool lds_ok = (eN <= CAP);
        if (INF32) {
            const float* h = (const float*)hin;
            float acc[4] = {0.f, 0.f, 0.f, 0.f};
            int i = b;
            if (lds_ok) {
                for (; i + 8 <= eN; i += 8) {
                    int s[8];
                    float4 w[8];
                    float hv[8];
#pragma unroll
                    for (int u = 0; u < 8; ++u) s[u] = Sld[i + u];
#pragma unroll
                    for (int u = 0; u < 8; ++u) w[u] = *(const float4*)(Wld + (i + u) * 4);
#pragma unroll
                    for (int u = 0; u < 8; ++u) hv[u] = h[(size_t)s[u] * 64 + lane];
#pragma unroll
                    for (int u = 0; u < 8; ++u) {
                        acc[0] += w[u].x * hv[u];
                        acc[1] += w[u].y * hv[u];
                        acc[2] += w[u].z * hv[u];
                        acc[3] += w[u].w * hv[u];
                    }
                }
                for (; i + 4 <= eN; i += 4) {
                    int s[4];
                    float4 w[4];
                    float hv[4];
#pragma unroll
                    for (int u = 0; u < 4; ++u) s[u] = Sld[i + u];
#pragma unroll
                    for (int u = 0; u < 4; ++u) w[u] = *(const float4*)(Wld + (i + u) * 4);
#pragma unroll
                    for (int u = 0; u < 4; ++u) hv[u] = h[(size_t)s[u] * 64 + lane];
#pragma unroll
                    for (int u = 0; u < 4; ++u) {
                        acc[0] += w[u].x * hv[u];
                        acc[1] += w[u].y * hv[u];
                        acc[2] += w[u].z * hv[u];
                        acc[3] += w[u].w * hv[u];
                    }
                }
                for (; i < eN; ++i) {
                    int s0 = Sld[i];
                    float4 w0 = *(const float4*)(Wld + i * 4);
                    float hv0 = h[(size_t)s0 * 64 + lane];
                    acc[0] += w0.x * hv0;
                    acc[1] += w0.y * hv0;
                    acc[2] += w0.z * hv0;
                    acc[3] += w0.w * hv0;
                }
            } else {
                for (; i < eN; ++i) {
                    int s0 = csr_src[base + i];
                    float4 w0 = *(const float4*)(csr_w + (size_t)(base + i) * 4);
                    float hv0 = h[(size_t)s0 * 64 + lane];
                    acc[0] += w0.x * hv0;
                    acc[1] += w0.y * hv0;
                    acc[2] += w0.z * hv0;
                    acc[3] += w0.w * hv0;
                }
            }
#pragma unroll
            for (int k = 0; k < 4; ++k) Ts[row * PITCH + k * 64 + lane] = f2bf(acc[k]);
        } else {
            const ushort* h = (const ushort*)hin;
            float a00 = 0.f, a01 = 0.f, a10 = 0.f, a11 = 0.f;
            float a20 = 0.f, a21 = 0.f, a30 = 0.f, a31 = 0.f;
            int i = b;
            if (lds_ok) {
                for (; i + 8 <= eN; i += 8) {
                    int s[8];
                    float4 w[8];
                    uint v[8];
#pragma unroll
                    for (int u = 0; u < 8; ++u) s[u] = Sld[i + u];
#pragma unroll
                    for (int u = 0; u < 8; ++u) w[u] = *(const float4*)(Wld + (i + u) * 4);
#pragma unroll
                    for (int u = 0; u < 8; ++u)
                        v[u] = *(const uint*)(h + (size_t)s[u] * 128 + lane * 2);
#pragma unroll
                    for (int u = 0; u < 8; ++u) {
                        float lo = bf2f_lo(v[u]), hi = bf2f_hi(v[u]);
                        a00 += w[u].x * lo; a01 += w[u].x * hi;
                        a10 += w[u].y * lo; a11 += w[u].y * hi;
                        a20 += w[u].z * lo; a21 += w[u].z * hi;
                        a30 += w[u].w * lo; a31 += w[u].w * hi;
                    }
                }
                for (; i + 4 <= eN; i += 4) {
                    int s[4];
                    float4 w[4];
                    uint v[4];
#pragma unroll
                    for (int u = 0; u < 4; ++u) s[u] = Sld[i + u];
#pragma unroll
                    for (int u = 0; u < 4; ++u) w[u] = *(const float4*)(Wld + (i + u) * 4);
#pragma unroll
                    for (int u = 0; u < 4; ++u)
                        v[u] = *(const uint*)(h + (size_t)s[u] * 128 + lane * 2);
#pragma unroll
                    for (int u = 0; u < 4; ++u) {
                        float lo = bf2f_lo(v[u]), hi = bf2f_hi(v[u]);
                        a00 += w[u].x * lo; a01 += w[u].x * hi;
                        a10 += w[u].y * lo; a11 += w[u].y * hi;
                        a20 += w[u].z * lo; a21 += w[u].z * hi;
                        a30 += w[u].w * lo; a31 += w[u].w * hi;
                    }
                }
                for (; i < eN; ++i) {
                    int s0 = Sld[i];
                    float4 w0 = *(const float4*)(Wld + i * 4);
                    uint v0 = *(const uint*)(h + (size_t)s0 * 128 + lane * 2);
                    float lo = bf2f_lo(v0), hi = bf2f_hi(v0);
                    a00 += w0.x * lo; a01 += w0.x * hi;
                    a10 += w0.y * lo; a11 += w0.y * hi;
                    a20 += w0.z * lo; a21 += w0.z * hi;
                    a30 += w0.w * lo; a31 += w0.w * hi;
                }
            } else {
                for (; i < eN; ++i) {
                    int s0 = csr_src[base + i];
                    float4 w0 = *(const float4*)(csr_w + (size_t)(base + i) * 4);
                    uint v0 = *(const uint*)(h + (size_t)s0 * 128 + lane * 2);
                    float lo = bf2f_lo(v0), hi = bf2f_hi(v0);
                    a00 += w0.x * lo; a01 += w0.x * hi;
                    a10 += w0.y * lo; a11 += w0.y * hi;
                    a20 += w0.z * lo; a21 += w0.z * hi;
                    a30 += w0.w * lo; a31 += w0.w * hi;
                }
            }
            ushort2 p;
            p.x = f2bf(a00); p.y = f2bf(a01);
            *(ushort2*)(Ts + row * PITCH + 0 * 128 + lane * 2) = p;
            p.x = f2bf(a10); p.y = f2bf(a11);
            *(ushort2*)(Ts + row * PITCH + 1 * 128 + lane * 2) = p;
            p.x = f2bf(a20); p.y = f2bf(a21);
            *(ushort2*)(Ts + row * PITCH + 2 * 128 + lane * 2) = p;
            p.x = f2bf(a30); p.y = f2bf(a31);
            *(ushort2*)(Ts + row * PITCH + 3 * 128 + lane * 2) = p;
        }
    }
    __syncthreads();

    // ---- GEMM phase: M=16 (tile), wave wv covers cols [32wv, 32wv+32) ----
    f32x4 acc[2];
    acc[0] = (f32x4){0.f, 0.f, 0.f, 0.f};
    acc[1] = (f32x4){0.f, 0.f, 0.f, 0.f};
    for (int k0 = 0; k0 < KD; k0 += 32) {
        bf16x8 af = *(const bf16x8*)(Ts + l16 * PITCH + k0 + quad * 8);
#pragma unroll
        for (int c = 0; c < 2; ++c) {
            int nr = wv * 32 + c * 16 + l16;
            bf16x8 bfr = *(const bf16x8*)(Bt + (size_t)nr * KD + k0 + quad * 8);
            acc[c] = __builtin_amdgcn_mfma_f32_16x16x32_bf16(af, bfr, acc[c], 0, 0, 0);
        }
    }
#pragma unroll
    for (int c = 0; c < 2; ++c) {
        int gn = wv * 32 + c * 16 + l16;
        float bv = bias[gn];
#pragma unroll
        for (int i = 0; i < 4; ++i) {
            int gm = nb + quad * 4 + i;
            float val = acc[c][i] + bv;
            if (OUTBF)
                ((ushort*)hout)[(size_t)gm * 128 + gn] = f2bf(val);
            else
                ((float*)hout)[(size_t)gm * 128 + gn] = val;
        }
    }
}

extern "C" void kernel_launch(void* const* d_in, const int* in_sizes, int n_in,
                              void* d_out, int out_size, void* d_ws, size_t ws_size,
                              hipStream_t stream) {
    const float* features = (const float*)d_in[0];
    const float* pseudo = (const float*)d_in[1];
    const int* src = (const int*)d_in[2];
    const int* dst = (const int*)d_in[3];
    const float* fc_w[3] = {(const float*)d_in[4], (const float*)d_in[10], (const float*)d_in[16]};
    const float* mu[3] = {(const float*)d_in[5], (const float*)d_in[11], (const float*)d_in[17]};
    const float* isg[3] = {(const float*)d_in[6], (const float*)d_in[12], (const float*)d_in[18]};
    const float* bias[3] = {(const float*)d_in[7], (const float*)d_in[13], (const float*)d_in[19]};
    const float* pw[3] = {(const float*)d_in[8], (const float*)d_in[14], (const float*)d_in[20]};
    const float* pb[3] = {(const float*)d_in[9], (const float*)d_in[15], (const float*)d_in[21]};

    char* ws = (char*)d_ws;
    auto alloc = [&](size_t bytes) -> void* {
        void* p = (void*)ws;
        ws += (bytes + 255) & ~(size_t)255;
        return p;
    };
    int* counts = (int*)alloc((size_t)(NN + 64) * 4);  // counts + done counter
    int* done = counts + NN;
    int* offsets = (int*)alloc((size_t)(NN + 1) * 4);
    int* cursor = (int*)alloc((size_t)NN * 4);
    int* csr_eidx = (int*)alloc((size_t)NE * 4);
    int* csr_src = (int*)alloc((size_t)NE * 4);
    float* csr_w = (float*)alloc((size_t)3 * NE * 4 * 4);
    ushort* w2t_0 = (ushort*)alloc((size_t)128 * 256 * 2);
    ushort* w2t_1 = (ushort*)alloc((size_t)128 * 512 * 2);
    ushort* w2t_2 = (ushort*)alloc((size_t)128 * 512 * 2);
    ushort* h1 = (ushort*)alloc((size_t)NN * 128 * 2);
    ushort* h2 = (ushort*)alloc((size_t)NN * 128 * 2);

    hipMemsetAsync(counts, 0, (size_t)(NN + 64) * 4, stream);
    count_scan<<<NE / 256, 256, 0, stream>>>(dst, counts, offsets, cursor, done);
    fill1_kernel<<<(NE + 255) / 256, 256, 0, stream>>>(dst, cursor, csr_eidx);

    EdgeParams P;
    P.pw0 = pw[0]; P.pb0 = pb[0]; P.mu0 = mu[0]; P.is0 = isg[0];
    P.pw1 = pw[1]; P.pb1 = pb[1]; P.mu1 = mu[1]; P.is1 = isg[1];
    P.pw2 = pw[2]; P.pb2 = pb[2]; P.mu2 = mu[2]; P.is2 = isg[2];
    fill2_prep<<<1890, 256, 0, stream>>>(csr_eidx, src, pseudo, P, csr_src, csr_w,
                                         fc_w[0], fc_w[1], fc_w[2], w2t_0, w2t_1, w2t_2);

    const int GB = NN / 16;  // 1250

    layer_fused<64, true, true><<<GB, 256, 0, stream>>>(
        features, offsets, csr_src, csr_w + (size_t)0 * NE * 4, w2t_0, bias[0], h1);
    layer_fused<128, false, true><<<GB, 256, 0, stream>>>(
        h1, offsets, csr_src, csr_w + (size_t)1 * NE * 4, w2t_1, bias[1], h2);
    layer_fused<128, false, false><<<GB, 256, 0, stream>>>(
        h2, offsets, csr_src, csr_w + (size_t)2 * NE * 4, w2t_2, bias[2], (float*)d_out);
}

// Round 9
// 281.645 us; speedup vs baseline: 1.1204x; 1.1204x over previous
//
#include <hip/hip_runtime.h>
#include <hip/hip_bf16.h>
#include <math.h>

#define NN 20000
#define NE 320000

typedef __attribute__((ext_vector_type(8))) short bf16x8;
typedef __attribute__((ext_vector_type(4))) float f32x4;

__device__ inline float bf2f_lo(uint v) {
    union { uint i; float f; } c; c.i = v << 16; return c.f;
}
__device__ inline float bf2f_hi(uint v) {
    union { uint i; float f; } c; c.i = v & 0xffff0000u; return c.f;
}
__device__ inline ushort f2bf(float f) {
    __hip_bfloat16 h = __float2bfloat16(f);
    return *reinterpret_cast<ushort*>(&h);
}

// ---------------- CSR build (r4 structure: fast, parallel) ----------------
__global__ void count_kernel(const int* __restrict__ dst, int* __restrict__ counts) {
    int e = blockIdx.x * blockDim.x + threadIdx.x;
    if (e < NE) atomicAdd(&counts[dst[e]], 1);
}

__global__ __launch_bounds__(1024) void scan_kernel(const int* __restrict__ counts,
                                                    int* __restrict__ offsets,
                                                    int* __restrict__ cursor) {
    __shared__ int part[1024];
    const int T = 1024, CHK = (NN + T - 1) / T;  // 20
    int t = threadIdx.x;
    int begin = t * CHK;
    int end = begin + CHK < NN ? begin + CHK : NN;
    int s = 0;
    for (int i = begin; i < end; ++i) s += counts[i];
    part[t] = s;
    __syncthreads();
    for (int off = 1; off < T; off <<= 1) {
        int v = (t >= off) ? part[t - off] : 0;
        __syncthreads();
        part[t] += v;
        __syncthreads();
    }
    int run = (t == 0) ? 0 : part[t - 1];
    for (int i = begin; i < end; ++i) {
        offsets[i] = run;
        cursor[i] = run;
        run += counts[i];
    }
    if (t == T - 1) offsets[NN] = part[T - 1];
}

// pass 1: scatter ONLY the 4-byte edge index into CSR position order
__global__ void fill1_kernel(const int* __restrict__ dst, int* __restrict__ cursor,
                             int* __restrict__ csr_eidx) {
    int e = blockIdx.x * blockDim.x + threadIdx.x;
    if (e >= NE) return;
    int pos = atomicAdd(&cursor[dst[e]], 1);
    csr_eidx[pos] = e;
}

struct EdgeParams {
    const float *pw0, *pb0, *mu0, *is0;
    const float *pw1, *pb1, *mu1, *is1;
    const float *pw2, *pb2, *mu2, *is2;
};

__device__ inline float fast_tanh(float x) {
    x = fminf(fmaxf(x, -9.f), 9.f);
    float e = __expf(2.f * x);
    return 1.f - 2.f / (e + 1.f);
}

__device__ inline void layer_w(float p0, float p1, const float* pw, const float* pb,
                               const float* mu, const float* is, float* out4) {
    float u0 = fast_tanh(p0 * pw[0] + p1 * pw[2] + pb[0]);
    float u1 = fast_tanh(p0 * pw[1] + p1 * pw[3] + pb[1]);
#pragma unroll
    for (int k = 0; k < 4; ++k) {
        float d0 = (u0 - mu[k * 2 + 0]) * is[k * 2 + 0];
        float d1 = (u1 - mu[k * 2 + 1]) * is[k * 2 + 1];
        out4[k] = __expf(-0.5f * (d0 * d0 + d1 * d1));
    }
}

// -------- fused: fill2 (blocks 0..1249) + weight transpose (blocks 1250..1889) --------
__global__ void fill2_prep(const int* __restrict__ csr_eidx, const int* __restrict__ src,
                           const float* __restrict__ pseudo, EdgeParams P,
                           int* __restrict__ csr_src, float* __restrict__ csr_w,
                           const float* __restrict__ f0, const float* __restrict__ f1,
                           const float* __restrict__ f2, ushort* __restrict__ w0,
                           ushort* __restrict__ w1, ushort* __restrict__ w2) {
    int bid = blockIdx.x;
    if (bid < 1250) {
        int i = bid * 256 + threadIdx.x;  // 1250*256 == NE exactly
        int e = csr_eidx[i];
        float2 p = *(const float2*)(pseudo + (size_t)e * 2);
        csr_src[i] = src[e];
        float w[4];
        layer_w(p.x, p.y, P.pw0, P.pb0, P.mu0, P.is0, w);
        *(float4*)(csr_w + (size_t)(0 * NE + i) * 4) = make_float4(w[0], w[1], w[2], w[3]);
        layer_w(p.x, p.y, P.pw1, P.pb1, P.mu1, P.is1, w);
        *(float4*)(csr_w + (size_t)(1 * NE + i) * 4) = make_float4(w[0], w[1], w[2], w[3]);
        layer_w(p.x, p.y, P.pw2, P.pb2, P.mu2, P.is2, w);
        *(float4*)(csr_w + (size_t)(2 * NE + i) * 4) = make_float4(w[0], w[1], w[2], w[3]);
    } else {
        int idx = (bid - 1250) * 256 + threadIdx.x;  // 640 blocks cover 163840 exactly
        const float* srcp;
        ushort* dstp;
        int din, KD, li;
        if (idx < 128 * 256) {
            srcp = f0; dstp = w0; din = 64; KD = 256; li = idx;
        } else if (idx < 128 * 256 + 128 * 512) {
            srcp = f1; dstp = w1; din = 128; KD = 512; li = idx - 128 * 256;
        } else {
            srcp = f2; dstp = w2; din = 128; KD = 512; li = idx - 128 * 256 - 128 * 512;
        }
        int n = li / KD;
        int r = li - n * KD;
        int k = r / din;
        int d = r - k * din;
        dstp[li] = f2bf(srcp[d * 512 + k * 128 + n]);
    }
}

// ---------------- fused layer: LDS-staged edge metadata + agg + MFMA GEMM ----------------
// block = 256 threads (4 waves), 16 nodes; wave w aggs nodes 4w..4w+3, then GEMM cols 32w..32w+31.
template <int DIN, bool INF32, bool OUTBF>
__global__ __launch_bounds__(256) void layer_fused(const void* __restrict__ hin,
                                                   const int* __restrict__ offsets,
                                                   const int* __restrict__ csr_src,
                                                   const float* __restrict__ csr_w,
                                                   const ushort* __restrict__ Bt,
                                                   const float* __restrict__ bias,
                                                   void* __restrict__ hout) {
    constexpr int KD = 4 * DIN;
    constexpr int PITCH = KD + 8;  // ushorts; 16B-aligned rows
    constexpr int CAP = 768;       // staged-edge capacity (mean/block = 256)
    __shared__ __align__(16) ushort Ts[16 * PITCH];
    __shared__ int Sld[CAP];
    __shared__ __align__(16) float Wld[CAP * 4];
    int wv = threadIdx.x >> 6, lane = threadIdx.x & 63;
    int l16 = lane & 15, quad = lane >> 4;
    int nb = blockIdx.x * 16;
    int base = offsets[nb];
    int Eblk = offsets[nb + 16] - base;

    // cooperative stage of this block's edge metadata (contiguous CSR range)
    int Estage = Eblk < CAP ? Eblk : CAP;
    for (int i = threadIdx.x; i < Estage; i += 256) {
        Sld[i] = csr_src[base + i];
        *(float4*)(Wld + i * 4) = *(const float4*)(csr_w + (size_t)(base + i) * 4);
    }
    __syncthreads();

    // ---- aggregation phase ----
#pragma unroll
    for (int j = 0; j < 4; ++j) {
        int row = wv * 4 + j;
        int n = nb + row;
        int b = offsets[n] - base, eN = offsets[n + 1] - base;
        bool lds_ok = (eN <= CAP);
        if (INF32) {
            const float* h = (const float*)hin;
            float acc[4] = {0.f, 0.f, 0.f, 0.f};
            int i = b;
            if (lds_ok) {
                for (; i + 8 <= eN; i += 8) {
                    int s[8];
                    float4 w[8];
                    float hv[8];
#pragma unroll
                    for (int u = 0; u < 8; ++u) s[u] = Sld[i + u];
#pragma unroll
                    for (int u = 0; u < 8; ++u) w[u] = *(const float4*)(Wld + (i + u) * 4);
#pragma unroll
                    for (int u = 0; u < 8; ++u) hv[u] = h[(size_t)s[u] * 64 + lane];
#pragma unroll
                    for (int u = 0; u < 8; ++u) {
                        acc[0] += w[u].x * hv[u];
                        acc[1] += w[u].y * hv[u];
                        acc[2] += w[u].z * hv[u];
                        acc[3] += w[u].w * hv[u];
                    }
                }
                for (; i + 4 <= eN; i += 4) {
                    int s[4];
                    float4 w[4];
                    float hv[4];
#pragma unroll
                    for (int u = 0; u < 4; ++u) s[u] = Sld[i + u];
#pragma unroll
                    for (int u = 0; u < 4; ++u) w[u] = *(const float4*)(Wld + (i + u) * 4);
#pragma unroll
                    for (int u = 0; u < 4; ++u) hv[u] = h[(size_t)s[u] * 64 + lane];
#pragma unroll
                    for (int u = 0; u < 4; ++u) {
                        acc[0] += w[u].x * hv[u];
                        acc[1] += w[u].y * hv[u];
                        acc[2] += w[u].z * hv[u];
                        acc[3] += w[u].w * hv[u];
                    }
                }
                for (; i < eN; ++i) {
                    int s0 = Sld[i];
                    float4 w0 = *(const float4*)(Wld + i * 4);
                    float hv0 = h[(size_t)s0 * 64 + lane];
                    acc[0] += w0.x * hv0;
                    acc[1] += w0.y * hv0;
                    acc[2] += w0.z * hv0;
                    acc[3] += w0.w * hv0;
                }
            } else {
                for (; i < eN; ++i) {
                    int s0 = csr_src[base + i];
                    float4 w0 = *(const float4*)(csr_w + (size_t)(base + i) * 4);
                    float hv0 = h[(size_t)s0 * 64 + lane];
                    acc[0] += w0.x * hv0;
                    acc[1] += w0.y * hv0;
                    acc[2] += w0.z * hv0;
                    acc[3] += w0.w * hv0;
                }
            }
#pragma unroll
            for (int k = 0; k < 4; ++k) Ts[row * PITCH + k * 64 + lane] = f2bf(acc[k]);
        } else {
            const ushort* h = (const ushort*)hin;
            float a00 = 0.f, a01 = 0.f, a10 = 0.f, a11 = 0.f;
            float a20 = 0.f, a21 = 0.f, a30 = 0.f, a31 = 0.f;
            int i = b;
            if (lds_ok) {
                for (; i + 8 <= eN; i += 8) {
                    int s[8];
                    float4 w[8];
                    uint v[8];
#pragma unroll
                    for (int u = 0; u < 8; ++u) s[u] = Sld[i + u];
#pragma unroll
                    for (int u = 0; u < 8; ++u) w[u] = *(const float4*)(Wld + (i + u) * 4);
#pragma unroll
                    for (int u = 0; u < 8; ++u)
                        v[u] = *(const uint*)(h + (size_t)s[u] * 128 + lane * 2);
#pragma unroll
                    for (int u = 0; u < 8; ++u) {
                        float lo = bf2f_lo(v[u]), hi = bf2f_hi(v[u]);
                        a00 += w[u].x * lo; a01 += w[u].x * hi;
                        a10 += w[u].y * lo; a11 += w[u].y * hi;
                        a20 += w[u].z * lo; a21 += w[u].z * hi;
                        a30 += w[u].w * lo; a31 += w[u].w * hi;
                    }
                }
                for (; i + 4 <= eN; i += 4) {
                    int s[4];
                    float4 w[4];
                    uint v[4];
#pragma unroll
                    for (int u = 0; u < 4; ++u) s[u] = Sld[i + u];
#pragma unroll
                    for (int u = 0; u < 4; ++u) w[u] = *(const float4*)(Wld + (i + u) * 4);
#pragma unroll
                    for (int u = 0; u < 4; ++u)
                        v[u] = *(const uint*)(h + (size_t)s[u] * 128 + lane * 2);
#pragma unroll
                    for (int u = 0; u < 4; ++u) {
                        float lo = bf2f_lo(v[u]), hi = bf2f_hi(v[u]);
                        a00 += w[u].x * lo; a01 += w[u].x * hi;
                        a10 += w[u].y * lo; a11 += w[u].y * hi;
                        a20 += w[u].z * lo; a21 += w[u].z * hi;
                        a30 += w[u].w * lo; a31 += w[u].w * hi;
                    }
                }
                for (; i < eN; ++i) {
                    int s0 = Sld[i];
                    float4 w0 = *(const float4*)(Wld + i * 4);
                    uint v0 = *(const uint*)(h + (size_t)s0 * 128 + lane * 2);
                    float lo = bf2f_lo(v0), hi = bf2f_hi(v0);
                    a00 += w0.x * lo; a01 += w0.x * hi;
                    a10 += w0.y * lo; a11 += w0.y * hi;
                    a20 += w0.z * lo; a21 += w0.z * hi;
                    a30 += w0.w * lo; a31 += w0.w * hi;
                }
            } else {
                for (; i < eN; ++i) {
                    int s0 = csr_src[base + i];
                    float4 w0 = *(const float4*)(csr_w + (size_t)(base + i) * 4);
                    uint v0 = *(const uint*)(h + (size_t)s0 * 128 + lane * 2);
                    float lo = bf2f_lo(v0), hi = bf2f_hi(v0);
                    a00 += w0.x * lo; a01 += w0.x * hi;
                    a10 += w0.y * lo; a11 += w0.y * hi;
                    a20 += w0.z * lo; a21 += w0.z * hi;
                    a30 += w0.w * lo; a31 += w0.w * hi;
                }
            }
            ushort2 p;
            p.x = f2bf(a00); p.y = f2bf(a01);
            *(ushort2*)(Ts + row * PITCH + 0 * 128 + lane * 2) = p;
            p.x = f2bf(a10); p.y = f2bf(a11);
            *(ushort2*)(Ts + row * PITCH + 1 * 128 + lane * 2) = p;
            p.x = f2bf(a20); p.y = f2bf(a21);
            *(ushort2*)(Ts + row * PITCH + 2 * 128 + lane * 2) = p;
            p.x = f2bf(a30); p.y = f2bf(a31);
            *(ushort2*)(Ts + row * PITCH + 3 * 128 + lane * 2) = p;
        }
    }
    __syncthreads();

    // ---- GEMM phase: M=16 (tile), wave wv covers cols [32wv, 32wv+32) ----
    f32x4 acc[2];
    acc[0] = (f32x4){0.f, 0.f, 0.f, 0.f};
    acc[1] = (f32x4){0.f, 0.f, 0.f, 0.f};
    for (int k0 = 0; k0 < KD; k0 += 32) {
        bf16x8 af = *(const bf16x8*)(Ts + l16 * PITCH + k0 + quad * 8);
#pragma unroll
        for (int c = 0; c < 2; ++c) {
            int nr = wv * 32 + c * 16 + l16;
            bf16x8 bfr = *(const bf16x8*)(Bt + (size_t)nr * KD + k0 + quad * 8);
            acc[c] = __builtin_amdgcn_mfma_f32_16x16x32_bf16(af, bfr, acc[c], 0, 0, 0);
        }
    }
#pragma unroll
    for (int c = 0; c < 2; ++c) {
        int gn = wv * 32 + c * 16 + l16;
        float bv = bias[gn];
#pragma unroll
        for (int i = 0; i < 4; ++i) {
            int gm = nb + quad * 4 + i;
            float val = acc[c][i] + bv;
            if (OUTBF)
                ((ushort*)hout)[(size_t)gm * 128 + gn] = f2bf(val);
            else
                ((float*)hout)[(size_t)gm * 128 + gn] = val;
        }
    }
}

extern "C" void kernel_launch(void* const* d_in, const int* in_sizes, int n_in,
                              void* d_out, int out_size, void* d_ws, size_t ws_size,
                              hipStream_t stream) {
    const float* features = (const float*)d_in[0];
    const float* pseudo = (const float*)d_in[1];
    const int* src = (const int*)d_in[2];
    const int* dst = (const int*)d_in[3];
    const float* fc_w[3] = {(const float*)d_in[4], (const float*)d_in[10], (const float*)d_in[16]};
    const float* mu[3] = {(const float*)d_in[5], (const float*)d_in[11], (const float*)d_in[17]};
    const float* isg[3] = {(const float*)d_in[6], (const float*)d_in[12], (const float*)d_in[18]};
    const float* bias[3] = {(const float*)d_in[7], (const float*)d_in[13], (const float*)d_in[19]};
    const float* pw[3] = {(const float*)d_in[8], (const float*)d_in[14], (const float*)d_in[20]};
    const float* pb[3] = {(const float*)d_in[9], (const float*)d_in[15], (const float*)d_in[21]};

    char* ws = (char*)d_ws;
    auto alloc = [&](size_t bytes) -> void* {
        void* p = (void*)ws;
        ws += (bytes + 255) & ~(size_t)255;
        return p;
    };
    int* counts = (int*)alloc((size_t)NN * 4);
    int* offsets = (int*)alloc((size_t)(NN + 1) * 4);
    int* cursor = (int*)alloc((size_t)NN * 4);
    int* csr_eidx = (int*)alloc((size_t)NE * 4);
    int* csr_src = (int*)alloc((size_t)NE * 4);
    float* csr_w = (float*)alloc((size_t)3 * NE * 4 * 4);
    ushort* w2t_0 = (ushort*)alloc((size_t)128 * 256 * 2);
    ushort* w2t_1 = (ushort*)alloc((size_t)128 * 512 * 2);
    ushort* w2t_2 = (ushort*)alloc((size_t)128 * 512 * 2);
    ushort* h1 = (ushort*)alloc((size_t)NN * 128 * 2);
    ushort* h2 = (ushort*)alloc((size_t)NN * 128 * 2);

    hipMemsetAsync(counts, 0, (size_t)NN * 4, stream);
    count_kernel<<<(NE + 255) / 256, 256, 0, stream>>>(dst, counts);
    scan_kernel<<<1, 1024, 0, stream>>>(counts, offsets, cursor);
    fill1_kernel<<<(NE + 255) / 256, 256, 0, stream>>>(dst, cursor, csr_eidx);

    EdgeParams P;
    P.pw0 = pw[0]; P.pb0 = pb[0]; P.mu0 = mu[0]; P.is0 = isg[0];
    P.pw1 = pw[1]; P.pb1 = pb[1]; P.mu1 = mu[1]; P.is1 = isg[1];
    P.pw2 = pw[2]; P.pb2 = pb[2]; P.mu2 = mu[2]; P.is2 = isg[2];
    fill2_prep<<<1890, 256, 0, stream>>>(csr_eidx, src, pseudo, P, csr_src, csr_w,
                                         fc_w[0], fc_w[1], fc_w[2], w2t_0, w2t_1, w2t_2);

    const int GB = NN / 16;  // 1250

    layer_fused<64, true, true><<<GB, 256, 0, stream>>>(
        features, offsets, csr_src, csr_w + (size_t)0 * NE * 4, w2t_0, bias[0], h1);
    layer_fused<128, false, true><<<GB, 256, 0, stream>>>(
        h1, offsets, csr_src, csr_w + (size_t)1 * NE * 4, w2t_1, bias[1], h2);
    layer_fused<128, false, false><<<GB, 256, 0, stream>>>(
        h2, offsets, csr_src, csr_w + (size_t)2 * NE * 4, w2t_2, bias[2], (float*)d_out);
}